// Round 2
// baseline (801.718 us; speedup 1.0000x reference)
//
#include <hip/hip_runtime.h>
#include <hip/hip_bf16.h>

// SPIL layer: B=8, N=4096, K=32, C=128, H=64, P=32
// R4: revert to R2's 3-blocks/CU single-buffer structure (R3 double-buffer
//     regressed: occupancy 3->2 + grid 8192->1024 killed the implicit
//     inter-block overlap that was already streaming HBM).
//     Fold phi-GEMM (feat_i) and s_i into spil_main: per-block 4x64 phi dot
//     (VALU, phi_w L2-resident) + 32-term s_i reduce, computed in the
//     C-write phase where they hide under LDS/vmcnt waits. Deletes the
//     phi_gemm dispatch, the 8MB feat round-trip, and the s_i round-trip.

#define Bq 8
#define Nq 4096
#define Kq 32
#define Cq 128
#define Hq 64

typedef __bf16 bf16x8 __attribute__((ext_vector_type(8)));
typedef float  f32x4  __attribute__((ext_vector_type(4)));

__device__ __forceinline__ unsigned short f2bf(float f) {
  __hip_bfloat16 h = __float2bfloat16(f);   // RNE
  return *reinterpret_cast<unsigned short*>(&h);
}
__device__ __forceinline__ float bf2f(unsigned short u) {
  return __uint_as_float(((unsigned int)u) << 16);
}

// ---------- prep: WcT[h][c] = [theta|z]^T bf16 ----------
__global__ __launch_bounds__(256) void prep_w(const float* __restrict__ theta_w,
                                              const float* __restrict__ z_w,
                                              unsigned short* __restrict__ WcT) {
  int idx = blockIdx.x * 256 + threadIdx.x;   // 0..16383
  int h = idx >> 7, c = idx & 127;
  float v = (h < 64) ? theta_w[c * 64 + h] : z_w[c * 64 + (h - 64)];
  WcT[idx] = f2bf(v);
}

// ---------- main: per block 4 n's (128 neighbor rows) ----------
// LDS 38656B: phase1 Xs[128][128]bf16 swizzled (32KB);
// phase2 outt[128][132]bf16 (33792B, overlaps Xs); smalls at [33792,38656).
__global__ __launch_bounds__(256, 3) void spil_main(
    const float* __restrict__ cxyz, const float* __restrict__ nxyz,
    const float* __restrict__ nf, const float* __restrict__ cf,
    const float* __restrict__ phi_w, const float* __restrict__ phi_b,
    const float* __restrict__ theta_b,
    const float* __restrict__ m1_w, const float* __restrict__ m1_b,
    const float* __restrict__ m2_w, const float* __restrict__ m2_b,
    const float* __restrict__ psi_w, const float* __restrict__ psi_b,
    const float* __restrict__ z_b,
    const unsigned short* __restrict__ WcT,
    float* __restrict__ out) {
  __shared__ __align__(16) char smem[38656];
  unsigned short* Xs   = (unsigned short*)smem;             // [128][128] swizzled
  unsigned short* outt = (unsigned short*)smem;             // [128][132]
  float* base   = (float*)(smem + 33792);
  float* feat_s = base;                                     // 256
  float* m2w_s  = base + 256;                               // 96
  float* m2b_s  = base + 352;                               // 32
  float* psij_s = base + 384;                               // 32
  float* zb_s   = base + 416;                               // 64
  float* tb_s   = base + 480;                               // 64
  float* m1w_s  = base + 544;                               // 96
  float* m1b_s  = base + 640;                               // 32
  float* psii_s = base + 672;                               // 32
  float* cf_s   = base + 704;                               // 512 (4 n x 128 c)

  const int t = threadIdx.x;
  const int wave = t >> 6, lane = t & 63;
  const int lo16 = lane & 15, quad = lane >> 4;
  const size_t n0 = (size_t)blockIdx.x * 4;                 // grid = B*N/4 = 8192

  // ---- W fragments from global (L2-resident 32KB), issued first
  const int mhalf = wave & 1, nhalf = wave >> 1;
  bf16x8 wf[4][4];
#pragma unroll
  for (int ks = 0; ks < 4; ks++)
#pragma unroll
    for (int nt = 0; nt < 4; nt++)
      wf[ks][nt] = *(const bf16x8*)(WcT + (size_t)(nhalf * 64 + nt * 16 + lo16) * 128 + ks * 32 + quad * 8);

  // ---- stage X: 128 rows x 128 cols fp32 -> bf16, XOR-swizzled granules
  const float4* xsrc = (const float4*)(nf + n0 * Kq * Cq);
  ushort4* xdst4 = (ushort4*)Xs;
#pragma unroll
  for (int i = 0; i < 16; i++) {
    int j = t + i * 256;
    float4 v = xsrc[j];
    int r = j >> 5, w = j & 31;
    int g = w >> 1, hf = w & 1;
    int p = g ^ (r & 15);
    ushort4 pk;
    pk.x = f2bf(v.x); pk.y = f2bf(v.y); pk.z = f2bf(v.z); pk.w = f2bf(v.w);
    xdst4[r * 32 + p * 2 + hf] = pk;
  }
  // ---- small constants + cf rows (visible after B0)
  if (t < 96) { m2w_s[t] = m2_w[t]; m1w_s[t] = m1_w[t]; }
  if (t < 32) { m2b_s[t] = m2_b[t]; psij_s[t] = psi_w[32 + t];
                m1b_s[t] = m1_b[t]; psii_s[t] = psi_w[t]; }
  if (t < 64) { zb_s[t] = z_b[t]; tb_s[t] = theta_b[t]; }
  if (t < 128) ((float4*)cf_s)[t] = ((const float4*)(cf + n0 * Cq))[t];
  __syncthreads();   // B0

  // ---- MFMA: wave covers 64 rows x 64 cols (4x4 tiles of 16x16x32), K=128
  f32x4 acc[4][4];
#pragma unroll
  for (int mt = 0; mt < 4; mt++)
#pragma unroll
    for (int nt = 0; nt < 4; nt++) acc[mt][nt] = (f32x4){0.f, 0.f, 0.f, 0.f};
#pragma unroll
  for (int ks = 0; ks < 4; ks++) {
    int p = (ks * 4 + quad) ^ lo16;
    bf16x8 a[4];
#pragma unroll
    for (int mt = 0; mt < 4; mt++) {
      int row = mhalf * 64 + mt * 16 + lo16;
      a[mt] = *(const bf16x8*)(Xs + row * 128 + p * 8);
    }
#pragma unroll
    for (int mt = 0; mt < 4; mt++)
#pragma unroll
      for (int nt = 0; nt < 4; nt++)
        acc[mt][nt] = __builtin_amdgcn_mfma_f32_16x16x32_bf16(a[mt], wf[ks][nt], acc[mt][nt], 0, 0, 0);
  }
  __syncthreads();   // B1: Xs dead; outt overlaps it

  // ---- write C to LDS (bf16, stride 132)
#pragma unroll
  for (int mt = 0; mt < 4; mt++) {
    int row0 = mhalf * 64 + mt * 16 + quad * 4;
#pragma unroll
    for (int nt = 0; nt < 4; nt++) {
      int col = nhalf * 64 + nt * 16 + lo16;
#pragma unroll
      for (int r = 0; r < 4; r++)
        outt[(row0 + r) * 132 + col] = f2bf(acc[mt][nt][r]);
    }
  }

  // ---- folded phi: wave computes feat_i for n = n0+wave, lane = h
  {
    const float* cfrow = cf_s + wave * 128;        // LDS broadcast reads
    float f = phi_b[lane];
#pragma unroll 8
    for (int c = 0; c < 128; c++)
      f = fmaf(cfrow[c], phi_w[c * 64 + lane], f); // phi_w L2-resident, coalesced
    feat_s[wave * 64 + lane] = fmaxf(f, 0.f);
  }

  // ---- folded s_i + epilogue operand loads for this wave's n
  const size_t ng = n0 + wave;
  const float cx = cxyz[ng * 3], cy = cxyz[ng * 3 + 1], cz = cxyz[ng * 3 + 2];
  float sI;
  {
    int p = lane & 31;
    float pi = fmaxf(fmaf(cx, m1w_s[p], fmaf(cy, m1w_s[32 + p], fmaf(cz, m1w_s[64 + p], m1b_s[p]))), 0.f);
    sI = pi * psii_s[p];
#pragma unroll
    for (int off = 16; off; off >>= 1) sI += __shfl_xor(sI, off);
  }
  __syncthreads();   // B2: outt + feat_s visible

  // ---- epilogue: wave w handles n = n0 + w; lanes: k = lane&31, h-half = lane>>5
  const int k = lane & 31, half = lane >> 5;
  const int baser = wave * 32;

  // r_f = dot(feat_i, relu(theta_out + theta_b)) / sqrt(64)
  const float* fi = feat_s + wave * 64;
  const unsigned short* orow = outt + (size_t)(baser + k) * 132;
  float v = 0.f;
#pragma unroll
  for (int i = 0; i < 32; i++) {
    int h = half * 32 + i;
    float fj = fmaxf(bf2f(orow[h]) + tb_s[h], 0.f);
    v = fmaf(fj, fi[h], v);
  }
  v += __shfl_xor(v, 32);
  float r_f = v * 0.125f;

  // positional score + SPIL mask
  const float* nxp = nxyz + (ng * Kq + (size_t)k) * 3;
  float xj = nxp[0], yj = nxp[1], zj = nxp[2];
  float sj = 0.f;
#pragma unroll
  for (int p = 0; p < 32; p++) {
    float pj = fmaxf(fmaf(xj, m2w_s[p], fmaf(yj, m2w_s[32 + p], fmaf(zj, m2w_s[64 + p], m2b_s[p]))), 0.f);
    sj = fmaf(pj, psij_s[p], sj);
  }
  float rl = fmaxf(sI + sj + psi_b[0], 0.f);
  float dx = cx - xj, dy = cy - yj, dz = cz - zj;
  float dist = sqrtf(dx * dx + dy * dy + dz * dz);
  if (cz == zj && dist > 0.04f) rl = 0.f;   // same_frame && far -> masked

  // masked, r_l-weighted softmax over K=32 (duplicated across lane halves)
  float m = r_f;
#pragma unroll
  for (int off = 16; off; off >>= 1) m = fmaxf(m, __shfl_xor(m, off));
  float e = rl * __expf(r_f - m);
  float s = e;
#pragma unroll
  for (int off = 16; off; off >>= 1) s += __shfl_xor(s, off);
  float wgt = e / (s + 1e-8f);

  // out[n][h] = sum_k wgt_k * (z_out[k][h] + z_b[h]); lane -> h
  const int h = lane;
  const float zb = zb_s[h];
  float o = 0.f;
#pragma unroll
  for (int kk = 0; kk < 32; kk++) {
    float w = __shfl(wgt, kk);
    o = fmaf(w, bf2f(outt[(baser + kk) * 132 + 64 + h]) + zb, o);
  }
  out[ng * 64 + h] = o;
}

extern "C" void kernel_launch(void* const* d_in, const int* in_sizes, int n_in,
                              void* d_out, int out_size, void* d_ws, size_t ws_size,
                              hipStream_t stream) {
  const float* cxyz    = (const float*)d_in[0];
  const float* cf      = (const float*)d_in[1];
  const float* nxyz    = (const float*)d_in[2];
  const float* nf      = (const float*)d_in[3];
  const float* phi_w   = (const float*)d_in[4];
  const float* phi_b   = (const float*)d_in[5];
  const float* theta_w = (const float*)d_in[6];
  const float* theta_b = (const float*)d_in[7];
  const float* m1_w    = (const float*)d_in[8];
  const float* m1_b    = (const float*)d_in[9];
  const float* m2_w    = (const float*)d_in[10];
  const float* m2_b    = (const float*)d_in[11];
  const float* psi_w   = (const float*)d_in[12];
  const float* psi_b   = (const float*)d_in[13];
  const float* z_w     = (const float*)d_in[14];
  const float* z_b     = (const float*)d_in[15];
  float* outp = (float*)d_out;

  // workspace: WcT (32KB)
  unsigned short* WcT = (unsigned short*)d_ws;

  prep_w<<<64, 256, 0, stream>>>(theta_w, z_w, WcT);
  spil_main<<<(Bq * Nq) / 4, 256, 0, stream>>>(cxyz, nxyz, nf, cf, phi_w, phi_b, theta_b,
                                               m1_w, m1_b, m2_w, m2_b, psi_w, psi_b, z_b,
                                               WcT, outp);
}